// Round 4
// baseline (1314.745 us; speedup 1.0000x reference)
//
#include <hip/hip_runtime.h>
#include <cstdint>

typedef unsigned short u16;
typedef __attribute__((ext_vector_type(8))) __bf16 bf16x8_t;
typedef __attribute__((ext_vector_type(4))) float f32x4_t;

constexpr int Bn = 8, Tn = 4096, Dn = 1024, Hn = 1024;
constexpr int Mn = Bn * Tn;            // 32768 rows

__device__ __forceinline__ u16 f2bf(float f) {
  uint32_t u = __builtin_bit_cast(uint32_t, f);
  u += 0x7FFFu + ((u >> 16) & 1u);   // RNE; inputs finite
  return (u16)(u >> 16);
}

// single launch converts x, Wz, Wh to bf16 AND zeroes the scan flags/counter
__global__ __launch_bounds__(256) void cvt_all(
    const float* __restrict__ x, const float* __restrict__ wz, const float* __restrict__ wh,
    u16* __restrict__ xb, u16* __restrict__ wzb, u16* __restrict__ whb,
    uint32_t* __restrict__ vcounter, uint32_t* __restrict__ flags) {
  int i = blockIdx.x * 256 + threadIdx.x;   // float4 index
  // zero the lookback state for this iteration (stream-ordered before gemm_scan)
  if (i < 4097) {
    if (i == 0) *vcounter = 0u;
    else        flags[i - 1] = 0u;          // 128 chains x 32 links
  }
  const float* s; u16* d; int off;
  if (i < 8388608)      { s = x;  d = xb;  off = i; }            // 32768*1024/4
  else if (i < 8650752) { s = wz; d = wzb; off = i - 8388608; }  // +1024*1024/4
  else                  { s = wh; d = whb; off = i - 8650752; }
  f32x4_t v = __builtin_nontemporal_load(&((const f32x4_t*)s)[off]);  // read-once
  ushort4 o;
  o.x = f2bf(v.x); o.y = f2bf(v.y); o.z = f2bf(v.z); o.w = f2bf(v.w);
  ((ushort4*)d)[off] = o;   // re-read soon by gemm: keep cached store
}

__device__ __forceinline__ void gl_lds16(const void* g, void* l) {
  __builtin_amdgcn_global_load_lds((const __attribute__((address_space(1))) void*)g,
                                   (__attribute__((address_space(3))) void*)l, 16u, 0, 0u);
}

__device__ __forceinline__ void gates(float kv, float tv, float& a, float& bb) {
  float e  = __expf(-kv);
  float rc = __builtin_amdgcn_rcpf(1.f + e);   // z = sigmoid(k)
  a = e * rc;                                  // 1-z, no cancellation
  float g = (tv >= 0.f) ? (tv + 0.5f)
                        : __builtin_amdgcn_rcpf(1.f + __expf(-tv));
  bb = rc * g;
}

// Fused dual NT GEMM + gate epilogue + SINGLE-PASS scan (decoupled lookback).
// Block: 128 m-rows x 64 h-cols. Wave w owns chunk (32 t-rows).
// Chains: (b, ht) -> 128 chains of 32 links (p = mt&31). Virtual block ids from a
// global atomic counter guarantee a block's chain predecessors have already
// STARTED (rocPRIM-style), so spinning on their prefix cannot deadlock.
// Prefix publish/poll uses agent-scope release/acquire (cross-XCD safe).
__global__ __launch_bounds__(256) void gemm_scan(
    const u16* __restrict__ A, const u16* __restrict__ Wz, const u16* __restrict__ Wh,
    const float* __restrict__ bz, const float* __restrict__ bh,
    float* __restrict__ out,
    uint32_t* __restrict__ vcounter, uint32_t* __restrict__ flags,
    float* __restrict__ prefA, float* __restrict__ prefB) {
  constexpr int K = 1024;

  __shared__ uint vidS;
  if (threadIdx.x == 0)
    vidS = __hip_atomic_fetch_add(vcounter, 1u, __ATOMIC_RELAXED, __HIP_MEMORY_SCOPE_AGENT);

  __shared__ u16 lA[128 * 32];       // 8 KB
  __shared__ u16 lB[2][64 * 32];     // 2 x 4 KB (Wz, Wh)
  __shared__ float aggL[4][64][2];   // per-chunk (A,B) per col, 2 KB
  __shared__ float carryL[64];       // scan value entering this block, per col

  __syncthreads();
  const uint bid = vidS;             // virtual id == dispatch-start order
  const uint xcd = bid & 7;
  const uint seq = bid >> 3;
  const uint ht  = seq & 15;               // 16 h-tiles fastest (W L2-resident)
  const uint mt  = (seq >> 4) * 8 + xcd;   // 256 m-tiles; chain pred has smaller vid
  const int m0 = mt * 128;
  const int h0 = ht * 64;

  const int tid  = threadIdx.x;
  const int lane = tid & 63;
  const int wave = tid >> 6;

  // ---- staging addresses (swizzled source column) ----
  const int csA = (((lane & 3) ^ ((lane >> 3) & 3)) * 8);   // elem offset
  const int csB = (((tid  & 3) ^ ((tid  >> 3) & 3)) * 8);
  const u16* gA0 = A  + (size_t)(m0 + wave * 16 + (lane >> 2)) * K + csA;
  const u16* gBz = Wz + (size_t)(h0 + (tid >> 2)) * K + csB;
  const u16* gBh = Wh + (size_t)(h0 + (tid >> 2)) * K + csB;
  u16* lAw  = lA    + wave * 512;   // wave-uniform LDS dest (u16 units)
  u16* lBw0 = lB[0] + wave * 512;
  u16* lBw1 = lB[1] + wave * 512;

  // ---- fragment read offsets (deswizzled) ----
  const int fr   = lane & 15;
  const int KB   = lane >> 4;
  const int fcol = (KB ^ ((fr >> 1) & 3)) * 8;   // u16 elems within row

  f32x4_t az[2][4] = {}, ah[2][4] = {};

  for (int kt = 0; kt < K; kt += 32) {
    gl_lds16(gA0 + kt,                    lAw);
    gl_lds16(gA0 + kt + (size_t)64 * K,   lAw + 2048);   // rows +64
    gl_lds16(gBz + kt,                    lBw0);
    gl_lds16(gBh + kt,                    lBw1);
    __syncthreads();
    bf16x8_t af[2], bzf[4], bhf[4];
#pragma unroll
    for (int i = 0; i < 2; ++i)
      af[i] = *(const bf16x8_t*)&lA[(wave * 32 + i * 16 + fr) * 32 + fcol];
#pragma unroll
    for (int j = 0; j < 4; ++j) {
      bzf[j] = *(const bf16x8_t*)&lB[0][(j * 16 + fr) * 32 + fcol];
      bhf[j] = *(const bf16x8_t*)&lB[1][(j * 16 + fr) * 32 + fcol];
    }
#pragma unroll
    for (int i = 0; i < 2; ++i)
#pragma unroll
      for (int j = 0; j < 4; ++j) {
        az[i][j] = __builtin_amdgcn_mfma_f32_16x16x32_bf16(af[i], bzf[j], az[i][j], 0, 0, 0);
        ah[i][j] = __builtin_amdgcn_mfma_f32_16x16x32_bf16(af[i], bhf[j], ah[i][j], 0, 0, 0);
      }
    __syncthreads();
  }

  // ---- epilogue pass 1: gates (packed, kept in regs) + chunk-local scans ----
  // C/D: col = lane&15, row = (lane>>4)*4 + reg  [m89-verified]
  const int cc = lane & 15;
  const int q  = lane >> 4;                  // quad within 16-row group
  const int b  = mt >> 5;                    // batch
  const int p  = mt & 31;                    // chain position
  const int chain = b * 16 + (int)ht;        // 0..127

  uint32_t pk[4][2][4];          // [j][i][r] packed fp16 (a | b<<16)
  float EA[4][2], EB[4][2];      // exclusive affine prefix within chunk, per (j,i)

#pragma unroll
  for (int j = 0; j < 4; ++j) {
    float bvz = bz[h0 + j * 16 + cc];
    float bvh = bh[h0 + j * 16 + cc];
    float FA0 = 1.f, FB0 = 0.f;  // full i=0 compose (broadcast)
#pragma unroll
    for (int i = 0; i < 2; ++i) {
      float A4 = 1.f, B4 = 0.f;  // this lane's quad compose
#pragma unroll
      for (int r = 0; r < 4; ++r) {
        float kv = az[i][j][r] + bvz;
        float tv = ah[i][j][r] + bvh;
        float a, bb;
        gates(kv, tv, a, bb);
        _Float16 a16 = (_Float16)a, b16 = (_Float16)bb;
        pk[j][i][r] = (uint32_t)__builtin_bit_cast(u16, a16) |
                      ((uint32_t)__builtin_bit_cast(u16, b16) << 16);
        float ar = (float)a16, br = (float)b16;   // ROUNDED gates everywhere
        B4 = fmaf(ar, B4, br);
        A4 = A4 * ar;
      }
      // inclusive scan over the 4 quads of this 16-row group (ordered, shfl_up)
      float IA = A4, IB = B4;
      float tA = __shfl_up(IA, 16), tB = __shfl_up(IB, 16);
      if (q >= 1) { IB = fmaf(IA, tB, IB); IA *= tA; }
      tA = __shfl_up(IA, 32); tB = __shfl_up(IB, 32);
      if (q >= 2) { IB = fmaf(IA, tB, IB); IA *= tA; }
      // exclusive within group
      float eA = __shfl_up(IA, 16), eB = __shfl_up(IB, 16);
      if (q == 0) { eA = 1.f; eB = 0.f; }
      if (i == 0) {
        EA[j][0] = eA; EB[j][0] = eB;
        FA0 = __shfl(IA, 48 + cc);   // inclusive at q=3 == full i0 compose
        FB0 = __shfl(IB, 48 + cc);
      } else {
        EA[j][1] = eA * FA0;                       // i=1 quads come after all i=0
        EB[j][1] = fmaf(eA, FB0, eB);
        if (q == 3) {                              // chunk aggregate = I1(q=3) ∘ I0full
          aggL[wave][j * 16 + cc][0] = IA * FA0;
          aggL[wave][j * 16 + cc][1] = fmaf(IA, FB0, IB);
        }
      }
    }
  }
  __syncthreads();

  // ---- wave 0: block aggregate, lookback, publish prefix, block carry ----
  if (wave == 0) {
    const int col = lane;   // 0..63
    float bA = aggL[0][col][0], bB = aggL[0][col][1];
#pragma unroll
    for (int w = 1; w < 4; ++w) {
      float cA = aggL[w][col][0], cB = aggL[w][col][1];
      bB = fmaf(cA, bB, cB);
      bA = cA * bA;
    }
    float vA = bA, vB = bB;   // prefix through end of this block
    float v0 = 0.f;           // scan value entering this block
    if (p > 0) {
      const uint32_t* fp = flags + chain * 32 + (p - 1);
      int spins = 0;
      while (__hip_atomic_load(fp, __ATOMIC_ACQUIRE, __HIP_MEMORY_SCOPE_AGENT) == 0u) {
        __builtin_amdgcn_s_sleep(8);
        if (++spins > (1 << 20)) break;   // bailout: wrong answer beats a hang
      }
      size_t pb = ((size_t)chain * 32 + (p - 1)) * 64 + col;
      uint32_t ua = __hip_atomic_load((const uint32_t*)(prefA + pb),
                                      __ATOMIC_RELAXED, __HIP_MEMORY_SCOPE_AGENT);
      uint32_t ub = __hip_atomic_load((const uint32_t*)(prefB + pb),
                                      __ATOMIC_RELAXED, __HIP_MEMORY_SCOPE_AGENT);
      float pA = __builtin_bit_cast(float, ua);
      float pB = __builtin_bit_cast(float, ub);
      v0 = pB;                               // initial state is 0 -> value = B
      vB = fmaf(bA, pB, bB);
      vA = bA * pA;
    }
    size_t ob = ((size_t)chain * 32 + p) * 64 + col;
    __hip_atomic_store((uint32_t*)(prefA + ob), __builtin_bit_cast(uint32_t, vA),
                       __ATOMIC_RELAXED, __HIP_MEMORY_SCOPE_AGENT);
    __hip_atomic_store((uint32_t*)(prefB + ob), __builtin_bit_cast(uint32_t, vB),
                       __ATOMIC_RELAXED, __HIP_MEMORY_SCOPE_AGENT);
    if (lane == 0)   // release orders the wave's prior stores before the flag
      __hip_atomic_store(flags + chain * 32 + p, 1u,
                         __ATOMIC_RELEASE, __HIP_MEMORY_SCOPE_AGENT);
    carryL[col] = v0;
  }
  __syncthreads();

  // ---- epilogue pass 2: apply scan in-register, stream out ----
#pragma unroll
  for (int j = 0; j < 4; ++j) {
    const int col = j * 16 + cc;
    float v = carryL[col];
    for (int w = 0; w < wave; ++w)         // carry through earlier chunks in block
      v = fmaf(aggL[w][col][0], v, aggL[w][col][1]);
#pragma unroll
    for (int i = 0; i < 2; ++i) {
      float h = fmaf(EA[j][i], v, EB[j][i]);   // state entering this lane's quad
#pragma unroll
      for (int r = 0; r < 4; ++r) {
        uint32_t w32 = pk[j][i][r];
        float a  = (float)__builtin_bit_cast(_Float16, (u16)(w32 & 0xFFFFu));
        float bb = (float)__builtin_bit_cast(_Float16, (u16)(w32 >> 16));
        h = fmaf(a, h, bb);
        __builtin_nontemporal_store(
            h, &out[(size_t)(m0 + wave * 32 + i * 16 + q * 4 + r) * Hn + h0 + col]);
      }
    }
  }
}

extern "C" void kernel_launch(void* const* d_in, const int* in_sizes, int n_in,
                              void* d_out, int out_size, void* d_ws, size_t ws_size,
                              hipStream_t stream) {
  const float* x  = (const float*)d_in[0];
  const float* Wz = (const float*)d_in[1];
  const float* bz = (const float*)d_in[2];
  const float* Wh = (const float*)d_in[3];
  const float* bh = (const float*)d_in[4];
  float* out = (float*)d_out;

  // ws layout (bytes):
  //   xbf     64 MB @ 0
  //   wzbf     2 MB @ 67108864
  //   whbf     2 MB @ 69206016
  //   counter  4  B @ 71303168   (virtual block id)
  //   flags   16 KB @ 71303424   ([128][32] u32)
  //   prefA    1 MB @ 71319808   ([128][32][64] f32)
  //   prefB    1 MB @ 72368384
  char* ws = (char*)d_ws;
  u16*      xbf   = (u16*)     (ws);
  u16*      wzbf  = (u16*)     (ws + 67108864);
  u16*      whbf  = (u16*)     (ws + 69206016);
  uint32_t* vcnt  = (uint32_t*)(ws + 71303168);
  uint32_t* flags = (uint32_t*)(ws + 71303424);
  float*    prefA = (float*)   (ws + 71319808);
  float*    prefB = (float*)   (ws + 72368384);

  cvt_all<<<dim3(34816), 256, 0, stream>>>(x, Wz, Wh, xbf, wzbf, whbf, vcnt, flags);
  gemm_scan<<<dim3(4096), 256, 0, stream>>>(xbf, wzbf, whbf, bz, bh, out,
                                            vcnt, flags, prefA, prefB);
}

// Round 6
// 439.798 us; speedup vs baseline: 2.9894x; 2.9894x over previous
//
#include <hip/hip_runtime.h>
#include <cstdint>

typedef unsigned short u16;
typedef __attribute__((ext_vector_type(8))) __bf16 bf16x8_t;
typedef __attribute__((ext_vector_type(4))) float f32x4_t;
typedef __attribute__((ext_vector_type(4))) uint32_t u32x4_t;

constexpr int Bn = 8, Tn = 4096, Dn = 1024, Hn = 1024;
constexpr int Mn = Bn * Tn;            // 32768 rows
constexpr int NC = 128, CL = Tn / NC;  // 128 chunks x 32 steps

__device__ __forceinline__ u16 f2bf(float f) {
  uint32_t u = __builtin_bit_cast(uint32_t, f);
  u += 0x7FFFu + ((u >> 16) & 1u);   // RNE; inputs finite
  return (u16)(u >> 16);
}

// single launch converts x, Wz, Wh to bf16
__global__ __launch_bounds__(256) void cvt_all(
    const float* __restrict__ x, const float* __restrict__ wz, const float* __restrict__ wh,
    u16* __restrict__ xb, u16* __restrict__ wzb, u16* __restrict__ whb) {
  int i = blockIdx.x * 256 + threadIdx.x;   // float4 index
  const float* s; u16* d; int off;
  if (i < 8388608)      { s = x;  d = xb;  off = i; }            // 32768*1024/4
  else if (i < 8650752) { s = wz; d = wzb; off = i - 8388608; }  // +1024*1024/4
  else                  { s = wh; d = whb; off = i - 8650752; }
  f32x4_t v = __builtin_nontemporal_load(&((const f32x4_t*)s)[off]);  // read-once
  ushort4 o;
  o.x = f2bf(v.x); o.y = f2bf(v.y); o.z = f2bf(v.z); o.w = f2bf(v.w);
  ((ushort4*)d)[off] = o;   // re-read soon by gemm: keep cached store
}

__device__ __forceinline__ void gl_lds16(const void* g, void* l) {
  __builtin_amdgcn_global_load_lds((const __attribute__((address_space(1))) void*)g,
                                   (__attribute__((address_space(3))) void*)l, 16u, 0, 0u);
}

__device__ __forceinline__ void gates(float kv, float tv, float& a, float& bb) {
  float e  = __expf(-kv);
  float rc = __builtin_amdgcn_rcpf(1.f + e);   // z = sigmoid(k)
  a = e * rc;                                  // 1-z, no cancellation
  float g = (tv >= 0.f) ? (tv + 0.5f)
                        : __builtin_amdgcn_rcpf(1.f + __expf(-tv));
  bb = rc * g;
}

// Fused dual NT GEMM + gate epilogue + per-chunk scan aggregates.
// Block: 128 m-rows x 64 h-cols, BOTH projections (Wz and Wh).
// Waves arranged 2x2: wave (wm,wh) owns 64 m-rows x 32 h-cols.
//   -> per 32-K step per wave: 8 ds_read_b128 (af4+bz2+bh2) for 16 MFMA
//      (was 10 for 16 with the 4x1 arrangement).
// BK=64 via two staged 32-col halves per barrier pair: half the barriers.
// LDS source-side swizzled (same scheme as before, per half).
__global__ __launch_bounds__(256) void gemm_fused(
    const u16* __restrict__ A, const u16* __restrict__ Wz, const u16* __restrict__ Wh,
    const float* __restrict__ bz, const float* __restrict__ bh,
    uint32_t* __restrict__ gAB, float* __restrict__ Aagg, float* __restrict__ Bagg) {
  constexpr int K = 1024;
  const uint bid = blockIdx.x;
  const uint xcd = bid & 7;
  const uint seq = bid >> 3;
  const uint ht  = seq & 15;               // 16 h-tiles fastest per XCD (W L2-resident)
  const uint mt  = (seq >> 4) * 8 + xcd;   // 256 m-tiles
  const int m0 = mt * 128;
  const int h0 = ht * 64;

  __shared__ u16 lA [2][128 * 32];   // 2 k-halves x 8 KB
  __shared__ u16 lBz[2][64 * 32];    // 2 k-halves x 4 KB
  __shared__ u16 lBh[2][64 * 32];

  const int tid  = threadIdx.x;
  const int lane = tid & 63;
  const int wave = tid >> 6;
  const int wm   = wave >> 1;        // row half (64 rows)
  const int wh   = wave & 1;         // col half (32 cols)

  // ---- staging addresses (swizzled source column) ----
  const int csA = (((lane & 3) ^ ((lane >> 3) & 3)) * 8);   // elem offset
  const int csB = (((tid  & 3) ^ ((tid  >> 3) & 3)) * 8);
  const u16* gA0 = A  + (size_t)(m0 + wave * 16 + (lane >> 2)) * K + csA;
  const u16* gBz = Wz + (size_t)(h0 + (tid >> 2)) * K + csB;
  const u16* gBh = Wh + (size_t)(h0 + (tid >> 2)) * K + csB;
  const int woff = wave * 512;       // wave-uniform LDS dest (u16 units)

  // ---- fragment read offsets (deswizzled) ----
  const int fr   = lane & 15;
  const int KB   = lane >> 4;
  const int fcol = (KB ^ ((fr >> 1) & 3)) * 8;   // u16 elems within row

  f32x4_t az[4][2] = {}, ah[4][2] = {};

  for (int kt = 0; kt < K; kt += 64) {
    // stage both 32-col halves, one barrier pair
    gl_lds16(gA0 + kt,                         lA[0] + woff);
    gl_lds16(gA0 + kt + (size_t)64 * K,        lA[0] + woff + 2048);   // rows +64
    gl_lds16(gA0 + kt + 32,                    lA[1] + woff);
    gl_lds16(gA0 + kt + 32 + (size_t)64 * K,   lA[1] + woff + 2048);
    gl_lds16(gBz + kt,                         lBz[0] + woff);
    gl_lds16(gBz + kt + 32,                    lBz[1] + woff);
    gl_lds16(gBh + kt,                         lBh[0] + woff);
    gl_lds16(gBh + kt + 32,                    lBh[1] + woff);
    __syncthreads();
#pragma unroll
    for (int half = 0; half < 2; ++half) {
      bf16x8_t af[4], bzf[2], bhf[2];
#pragma unroll
      for (int i = 0; i < 4; ++i)
        af[i] = *(const bf16x8_t*)&lA[half][(wm * 64 + i * 16 + fr) * 32 + fcol];
#pragma unroll
      for (int j = 0; j < 2; ++j) {
        bzf[j] = *(const bf16x8_t*)&lBz[half][(wh * 32 + j * 16 + fr) * 32 + fcol];
        bhf[j] = *(const bf16x8_t*)&lBh[half][(wh * 32 + j * 16 + fr) * 32 + fcol];
      }
#pragma unroll
      for (int i = 0; i < 4; ++i)
#pragma unroll
        for (int j = 0; j < 2; ++j) {
          az[i][j] = __builtin_amdgcn_mfma_f32_16x16x32_bf16(af[i], bzf[j], az[i][j], 0, 0, 0);
          ah[i][j] = __builtin_amdgcn_mfma_f32_16x16x32_bf16(af[i], bhf[j], ah[i][j], 0, 0, 0);
        }
    }
    __syncthreads();
  }

  // ---- epilogue: gates + packed store + ordered affine composition ----
  // C/D: col = lane&15, row = (lane>>4)*4 + reg  [m89-verified]
  const int cr = (lane >> 4) * 4;   // q*4
  const int cc = lane & 15;
  const int b  = mt >> 5;           // batch
  // wave (wm) rows [wm*64, wm*64+64) = chunks tc0 = (mt&31)*4 + wm*2 {+0,+1}

#pragma unroll
  for (int j = 0; j < 2; ++j) {
    float bvz = bz[h0 + wh * 32 + j * 16 + cc];
    float bvh = bh[h0 + wh * 32 + j * 16 + cc];
#pragma unroll
    for (int cp = 0; cp < 2; ++cp) {        // chunk within this wave's 64 rows
      float Ai[2], Bi[2];
#pragma unroll
      for (int i2 = 0; i2 < 2; ++i2) {      // 16-row group within chunk
        const int i = cp * 2 + i2;
        float Al = 1.f, Bl = 0.f;
#pragma unroll
        for (int r = 0; r < 4; ++r) {
          float kv = az[i][j][r] + bvz;
          float tv = ah[i][j][r] + bvh;
          float a, bb;
          gates(kv, tv, a, bb);
          _Float16 a16 = (_Float16)a, b16 = (_Float16)bb;
          uint32_t pk = (uint32_t)__builtin_bit_cast(u16, a16) |
                        ((uint32_t)__builtin_bit_cast(u16, b16) << 16);
          __builtin_nontemporal_store(
              pk, &gAB[(size_t)(m0 + wm * 64 + i * 16 + cr + r) * Hn +
                       h0 + wh * 32 + j * 16 + cc]);
          float ar = (float)a16, br = (float)b16;   // aggregate with ROUNDED gates
          Al = Al * ar;
          Bl = fmaf(ar, Bl, br);
        }
        // ordered composition across lane-quads (rows ascend with q)
        float Ahi = __shfl_down(Al, 16), Bhi = __shfl_down(Bl, 16);
        float A2 = Ahi * Al;
        float B2 = fmaf(Ahi, Bl, Bhi);
        Ahi = __shfl_down(A2, 32); Bhi = __shfl_down(B2, 32);
        Ai[i2] = Ahi * A2;
        Bi[i2] = fmaf(Ahi, B2, Bhi);
      }
      float Aw = Ai[1] * Ai[0];             // i2=1 rows are later
      float Bw = fmaf(Ai[1], Bi[0], Bi[1]);
      if (lane < 16) {
        const int tc = (mt & 31) * 4 + wm * 2 + cp;
        size_t ai = ((size_t)(b * NC + tc)) * Hn + h0 + wh * 32 + j * 16 + lane;
        Aagg[ai] = Aw;
        Bagg[ai] = Bw;
      }
    }
  }
}

// Phase B: serial scan of chunk aggregates -> carry per chunk. grid (16, B), 64 thr.
// carry MAY alias Aagg (read-before-write, same thread, same idx).
// Batched register prefetch (PF=16) keeps the alias from serializing 128
// HBM-latency iterations.
__global__ __launch_bounds__(64) void scan_phase_b(
    const float* Aagg, const float* __restrict__ Bagg, float* carry) {
  int h = blockIdx.x * 64 + threadIdx.x;
  int b = blockIdx.y;
  const size_t base = (size_t)b * NC * Hn + h;
  float state = 0.f;
  constexpr int PF = 16;
  float Av[PF], Bv[PF];
  for (int g = 0; g < NC; g += PF) {
#pragma unroll
    for (int u = 0; u < PF; ++u) {
      size_t idx = base + (size_t)(g + u) * Hn;
      Av[u] = Aagg[idx];
      Bv[u] = Bagg[idx];
    }
#pragma unroll
    for (int u = 0; u < PF; ++u) {
      size_t idx = base + (size_t)(g + u) * Hn;
      carry[idx] = state;
      state = fmaf(Av[u], state, Bv[u]);
    }
  }
}

// Phase C: pure fma stream over packed fp16 gates. grid (NC, B), 256 thr, 4 h/thr.
__global__ __launch_bounds__(256) void scan_phase_c(
    const uint32_t* __restrict__ gAB, const float* __restrict__ carry,
    float* __restrict__ out) {
  int h0 = threadIdx.x * 4;
  int c = blockIdx.x, b = blockIdx.y;
  f32x4_t hst = *(const f32x4_t*)(carry + ((size_t)(b * NC + c)) * Hn + h0);
  size_t base = ((size_t)b * Tn + (size_t)c * CL) * Hn + h0;
#pragma unroll 4
  for (int t = 0; t < CL; ++t) {
    size_t idx = base + (size_t)t * Hn;
    u32x4_t v = __builtin_nontemporal_load((const u32x4_t*)(gAB + idx));  // read-once
    uint32_t vv[4] = {v.x, v.y, v.z, v.w};
#pragma unroll
    for (int u = 0; u < 4; ++u) {
      float a = (float)__builtin_bit_cast(_Float16, (u16)(vv[u] & 0xFFFFu));
      float bb = (float)__builtin_bit_cast(_Float16, (u16)(vv[u] >> 16));
      hst[u] = fmaf(a, hst[u], bb);
    }
    __builtin_nontemporal_store(hst, (f32x4_t*)(out + idx));  // write-once
  }
}

extern "C" void kernel_launch(void* const* d_in, const int* in_sizes, int n_in,
                              void* d_out, int out_size, void* d_ws, size_t ws_size,
                              hipStream_t stream) {
  const float* x  = (const float*)d_in[0];
  const float* Wz = (const float*)d_in[1];
  const float* bz = (const float*)d_in[2];
  const float* Wh = (const float*)d_in[3];
  const float* bh = (const float*)d_in[4];
  float* out = (float*)d_out;

  // ws layout (bytes):
  //   xbf   64 MB @ 0
  //   wzbf   2 MB @ 67108864
  //   whbf   2 MB @ 69206016
  //   gAB  128 MB @ 71303168   ([M,H] u32 = fp16 a | b<<16)
  //   Aagg   4 MB @ 205520896  ([B,NC,H] fp32; carry aliases after phase B)
  //   Bagg   4 MB @ 209715200
  char* ws = (char*)d_ws;
  u16*      xbf   = (u16*)     (ws);
  u16*      wzbf  = (u16*)     (ws + 67108864);
  u16*      whbf  = (u16*)     (ws + 69206016);
  uint32_t* gAB   = (uint32_t*)(ws + 71303168);
  float*    Aagg  = (float*)   (ws + 205520896);
  float*    Bagg  = (float*)   (ws + 209715200);
  float*    carry = Aagg;   // safe alias

  cvt_all<<<dim3(34816), 256, 0, stream>>>(x, Wz, Wh, xbf, wzbf, whbf);
  gemm_fused<<<dim3(4096), 256, 0, stream>>>(xbf, wzbf, whbf, bz, bh, gAB, Aagg, Bagg);
  scan_phase_b<<<dim3(16, Bn), 64, 0, stream>>>(Aagg, Bagg, carry);
  scan_phase_c<<<dim3(NC, Bn), 256, 0, stream>>>(gAB, carry, out);
}